// Round 5
// baseline (172.246 us; speedup 1.0000x reference)
//
#include <hip/hip_runtime.h>
#include <math.h>

// Problem constants (fixed by setup_inputs)
#define NP 8192      // pred vertices
#define NG 12000     // gt vertices
#define NFP 16384    // pred faces
#define NFG 24000    // gt faces
#define EPSF 1e-6f

// uniform grid for NN: 16^3 cells over [0,1]^3, ~3 gt / ~2 pred per cell
#define GR 16
#define NC (GR*GR*GR)        // 4096
#define HCELL 0.0625f        // 1/16, exact power of two

// ---- workspace layout (bytes) ----
static constexpr size_t OFF_STARTP = 0;        // 4096 u32 cell start (pred)
static constexpr size_t OFF_CURP   = 16384;    // 4096 u32 cursor -> end after scatter
static constexpr size_t OFF_STARTG = 32768;    // 4096 u32 cell start (gt)
static constexpr size_t OFF_CURG   = 49152;    // 4096 u32 cursor -> end
static constexpr size_t OFF_SORTP  = 65536;    // 8192  float4 (x,y,z,idx-as-float-bits)
static constexpr size_t OFF_SORTG  = 196608;   // 12000 float4
static constexpr size_t OFF_GTN    = 388608;   // NG*3 f32 gt normal accum (raw)
static constexpr size_t OFF_PNN    = 532608;   // NP*3 f32 pred normal accum
static constexpr size_t OFF_NSUM   = 630912;   // NP*3 f32 laplacian neighbor sum
static constexpr size_t OFF_DEG    = 729216;   // NP   f32 laplacian degree
static constexpr size_t OFF_SCAL   = 761984;   // 7 f32 [sum_row,sum_col,pc,SX,SY,sse,lap]
static constexpr size_t OFF_TICKET = 762012;   // 1 u32
#define N_ZERO 93352   // floats from OFF_GTN through ticket (contiguous)

__device__ __forceinline__ int cell_of(float x) {
    int c = (int)(x * (float)GR);
    return min(max(c, 0), GR - 1);
}

// Dispatch 1: block 0 = histogram + prefix scan of both point sets (LDS);
//             blocks >=1 = zero the accumulator region.
__global__ __launch_bounds__(1024) void build_kernel(const float* __restrict__ pred,
                                                     const float* __restrict__ gt,
                                                     unsigned* __restrict__ startP,
                                                     unsigned* __restrict__ curP,
                                                     unsigned* __restrict__ startG,
                                                     unsigned* __restrict__ curG,
                                                     float* __restrict__ zero) {
    if (blockIdx.x == 0) {
        __shared__ unsigned hP[NC];
        __shared__ unsigned hG[NC];
        __shared__ unsigned ps[1024];
        int t = threadIdx.x;
        for (int i = t; i < NC; i += 1024) { hP[i] = 0u; hG[i] = 0u; }
        __syncthreads();
        for (int i = t; i < NP; i += 1024) {
            int c = (cell_of(pred[3*i+2]) * GR + cell_of(pred[3*i+1])) * GR + cell_of(pred[3*i]);
            atomicAdd(&hP[c], 1u);
        }
        for (int i = t; i < NG; i += 1024) {
            int c = (cell_of(gt[3*i+2]) * GR + cell_of(gt[3*i+1])) * GR + cell_of(gt[3*i]);
            atomicAdd(&hG[c], 1u);
        }
        __syncthreads();
        // exclusive scan of hP (4 elems/thread + Hillis-Steele on 1024 partials)
        {
            unsigned a0 = hP[4*t], a1 = hP[4*t+1], a2 = hP[4*t+2], a3 = hP[4*t+3];
            unsigned tsum = a0 + a1 + a2 + a3;
            ps[t] = tsum; __syncthreads();
            for (int off = 1; off < 1024; off <<= 1) {
                unsigned v = (t >= off) ? ps[t - off] : 0u;
                __syncthreads();
                ps[t] += v;
                __syncthreads();
            }
            unsigned ex = ps[t] - tsum;
            hP[4*t] = ex; hP[4*t+1] = ex + a0; hP[4*t+2] = ex + a0 + a1; hP[4*t+3] = ex + a0 + a1 + a2;
            __syncthreads();
            for (int i = t; i < NC; i += 1024) { startP[i] = hP[i]; curP[i] = hP[i]; }
            __syncthreads();
        }
        // exclusive scan of hG
        {
            unsigned a0 = hG[4*t], a1 = hG[4*t+1], a2 = hG[4*t+2], a3 = hG[4*t+3];
            unsigned tsum = a0 + a1 + a2 + a3;
            ps[t] = tsum; __syncthreads();
            for (int off = 1; off < 1024; off <<= 1) {
                unsigned v = (t >= off) ? ps[t - off] : 0u;
                __syncthreads();
                ps[t] += v;
                __syncthreads();
            }
            unsigned ex = ps[t] - tsum;
            hG[4*t] = ex; hG[4*t+1] = ex + a0; hG[4*t+2] = ex + a0 + a1; hG[4*t+3] = ex + a0 + a1 + a2;
            __syncthreads();
            for (int i = t; i < NC; i += 1024) { startG[i] = hG[i]; curG[i] = hG[i]; }
        }
    } else {
        int i = (blockIdx.x - 1) * 1024 + threadIdx.x;
        if (i < N_ZERO) zero[i] = 0.0f;
    }
}

// Dispatch 2: scatter points into cell-sorted arrays + face-normal/laplacian scatter.
#define SCAT_P_BLOCKS 32                        // 8192/256
#define SCAT_G_BLOCKS 47                        // ceil(12000/256)
#define SCAT_BLOCKS (SCAT_P_BLOCKS + SCAT_G_BLOCKS)
#define FACE_BLOCKS ((NFG + NFP + 255) / 256)   // 158
__global__ __launch_bounds__(256) void scatter_faces_kernel(const float* __restrict__ pred,
                                                            const int* __restrict__ pf,
                                                            const float* __restrict__ gt,
                                                            const int* __restrict__ gf,
                                                            unsigned* __restrict__ curP,
                                                            unsigned* __restrict__ curG,
                                                            float4* __restrict__ sortP,
                                                            float4* __restrict__ sortG,
                                                            float* __restrict__ gtn,
                                                            float* __restrict__ pnn,
                                                            float* __restrict__ nsum,
                                                            float* __restrict__ deg) {
    int b = blockIdx.x;
    if (b < SCAT_P_BLOCKS) {
        int i = b * 256 + threadIdx.x;            // < 8192 always
        float x = pred[3*i], y = pred[3*i+1], z = pred[3*i+2];
        int c = (cell_of(z) * GR + cell_of(y)) * GR + cell_of(x);
        unsigned pos = atomicAdd(&curP[c], 1u);
        sortP[pos] = make_float4(x, y, z, __int_as_float(i));
    } else if (b < SCAT_BLOCKS) {
        int i = (b - SCAT_P_BLOCKS) * 256 + threadIdx.x;
        if (i < NG) {
            float x = gt[3*i], y = gt[3*i+1], z = gt[3*i+2];
            int c = (cell_of(z) * GR + cell_of(y)) * GR + cell_of(x);
            unsigned pos = atomicAdd(&curG[c], 1u);
            sortG[pos] = make_float4(x, y, z, __int_as_float(i));
        }
    } else {
        int t = (b - SCAT_BLOCKS) * 256 + threadIdx.x;
        if (t < NFG) {
            int i0 = gf[3*t], i1 = gf[3*t+1], i2 = gf[3*t+2];
            float ax = gt[3*i0], ay = gt[3*i0+1], az = gt[3*i0+2];
            float bx = gt[3*i1], by = gt[3*i1+1], bz = gt[3*i1+2];
            float cx = gt[3*i2], cy = gt[3*i2+1], cz = gt[3*i2+2];
            float ux = bx-ax, uy = by-ay, uz = bz-az;
            float wx = cx-ax, wy = cy-ay, wz = cz-az;
            float nx = uy*wz - uz*wy, ny = uz*wx - ux*wz, nz = ux*wy - uy*wx;
            atomicAdd(&gtn[3*i0+0], nx); atomicAdd(&gtn[3*i0+1], ny); atomicAdd(&gtn[3*i0+2], nz);
            atomicAdd(&gtn[3*i1+0], nx); atomicAdd(&gtn[3*i1+1], ny); atomicAdd(&gtn[3*i1+2], nz);
            atomicAdd(&gtn[3*i2+0], nx); atomicAdd(&gtn[3*i2+1], ny); atomicAdd(&gtn[3*i2+2], nz);
        } else if (t < NFG + NFP) {
            int u = t - NFG;
            int i0 = pf[3*u], i1 = pf[3*u+1], i2 = pf[3*u+2];
            float ax = pred[3*i0], ay = pred[3*i0+1], az = pred[3*i0+2];
            float bx = pred[3*i1], by = pred[3*i1+1], bz = pred[3*i1+2];
            float cx = pred[3*i2], cy = pred[3*i2+1], cz = pred[3*i2+2];
            float ux = bx-ax, uy = by-ay, uz = bz-az;
            float wx = cx-ax, wy = cy-ay, wz = cz-az;
            float nx = uy*wz - uz*wy, ny = uz*wx - ux*wz, nz = ux*wy - uy*wx;
            atomicAdd(&pnn[3*i0+0], nx); atomicAdd(&pnn[3*i0+1], ny); atomicAdd(&pnn[3*i0+2], nz);
            atomicAdd(&pnn[3*i1+0], nx); atomicAdd(&pnn[3*i1+1], ny); atomicAdd(&pnn[3*i1+2], nz);
            atomicAdd(&pnn[3*i2+0], nx); atomicAdd(&pnn[3*i2+1], ny); atomicAdd(&pnn[3*i2+2], nz);
            atomicAdd(&nsum[3*i0+0], bx+cx); atomicAdd(&nsum[3*i0+1], by+cy); atomicAdd(&nsum[3*i0+2], bz+cz);
            atomicAdd(&nsum[3*i1+0], cx+ax); atomicAdd(&nsum[3*i1+1], cy+ay); atomicAdd(&nsum[3*i1+2], cz+az);
            atomicAdd(&nsum[3*i2+0], ax+bx); atomicAdd(&nsum[3*i2+1], ay+by); atomicAdd(&nsum[3*i2+2], az+bz);
            atomicAdd(&deg[i0], 2.0f); atomicAdd(&deg[i1], 2.0f); atomicAdd(&deg[i2], 2.0f);
        }
    }
}

__device__ __forceinline__ float wave_sum(float x) {
    #pragma unroll
    for (int o = 32; o > 0; o >>= 1) x += __shfl_down(x, o, 64);
    return x;
}

// Expanding-shell NN over a cell-sorted point set. Returns min d2 (and argmin
// original index if track_idx). Lexicographic (d2, idx) tie-break == reference
// first-occurrence argmin. Bound: any point outside the scanned box is at
// least `blo` away (per-axis distance to box face; faces at the domain border
// have nothing beyond them -> +inf).
__device__ __forceinline__ void grid_nn(float px, float py, float pz,
                                        const float4* __restrict__ S,
                                        const unsigned* __restrict__ cstart,
                                        const unsigned* __restrict__ cend,
                                        bool track_idx,
                                        float& best_out, int& bi_out) {
    int cx = cell_of(px), cy = cell_of(py), cz = cell_of(pz);
    float best = 3.0e38f;
    int bi = 0x7fffffff;
    for (int r = 0; r < GR; ++r) {
        int zlo = max(cz - r, 0), zhi = min(cz + r, GR - 1);
        int ylo = max(cy - r, 0), yhi = min(cy + r, GR - 1);
        int xlo = max(cx - r, 0), xhi = min(cx + r, GR - 1);
        for (int z = zlo; z <= zhi; ++z) {
            int az = abs(z - cz);
            for (int y = ylo; y <= yhi; ++y) {
                int ay = abs(y - cy);
                for (int x = xlo; x <= xhi; ++x) {
                    int ax = abs(x - cx);
                    int cheb = max(ax, max(ay, az));
                    if (cheb != r) continue;   // shell only
                    int c = (z * GR + y) * GR + x;
                    unsigned s0 = cstart[c], s1 = cend[c];
                    for (unsigned t = s0; t < s1; ++t) {
                        float4 q = S[t];
                        float dx = px - q.x, dy = py - q.y, dz = pz - q.z;
                        float d2 = fmaf(dx, dx, fmaf(dy, dy, dz*dz));
                        int qi = __float_as_int(q.w);
                        if (d2 < best || (track_idx && d2 == best && qi < bi)) {
                            best = d2; bi = qi;
                        }
                    }
                }
            }
        }
        if (best < 3.0e38f) {
            float blo = 1.0e30f;
            if (cx - r > 0)      blo = fminf(blo, px - (float)(cx - r) * HCELL);
            if (cx + r < GR - 1) blo = fminf(blo, (float)(cx + r + 1) * HCELL - px);
            if (cy - r > 0)      blo = fminf(blo, py - (float)(cy - r) * HCELL);
            if (cy + r < GR - 1) blo = fminf(blo, (float)(cy + r + 1) * HCELL - py);
            if (cz - r > 0)      blo = fminf(blo, pz - (float)(cz - r) * HCELL);
            if (cz + r < GR - 1) blo = fminf(blo, (float)(cz + r + 1) * HCELL - pz);
            if (blo >= 1.0e29f || best <= blo * blo) break;  // box covers grid, or bound met
        }
    }
    best_out = best;
    bi_out = bi;
}

// Dispatch 3: NN query (cell-sorted order for coherent walks) fused with all
// finalize terms; blocks [0,32) pred side, [32,79) gt side; last block combines.
#define FIN_PRED_BLOCKS 32
#define FIN_COL_BLOCKS 47
#define FIN_TOTAL (FIN_PRED_BLOCKS + FIN_COL_BLOCKS)
__global__ __launch_bounds__(256) void query_finalize_kernel(const float* __restrict__ relpos,
                                                             const int* __restrict__ label,
                                                             const float4* __restrict__ sortP,
                                                             const float4* __restrict__ sortG,
                                                             const unsigned* __restrict__ startP,
                                                             const unsigned* __restrict__ endP,
                                                             const unsigned* __restrict__ startG,
                                                             const unsigned* __restrict__ endG,
                                                             const float* __restrict__ pnn,
                                                             const float* __restrict__ gtn,
                                                             const float* __restrict__ nsum,
                                                             const float* __restrict__ deg,
                                                             float* __restrict__ scal,
                                                             unsigned* __restrict__ ticket,
                                                             float* __restrict__ out) {
    if (blockIdx.x < FIN_PRED_BLOCKS) {
        int i = blockIdx.x * 256 + threadIdx.x;    // < 8192, sorted order
        float4 P = sortP[i];
        int v = __float_as_int(P.w);               // original pred index
        float px = P.x, py = P.y, pz = P.z;

        float dmin; int nearest;
        grid_nn(px, py, pz, sortG, startG, endG, true, dmin, nearest);

        // normal consistency (normalize both accumulators on the fly)
        float ax = pnn[3*v], ay = pnn[3*v+1], az = pnn[3*v+2];
        float an = fmaxf(sqrtf(ax*ax + ay*ay + az*az), EPSF);
        float gx = gtn[3*nearest], gy = gtn[3*nearest+1], gz = gtn[3*nearest+2];
        float gn = fmaxf(sqrtf(gx*gx + gy*gy + gz*gz), EPSF);
        float nx = ax/an - gx/gn, ny = ay/an - gy/gn, nz = az/an - gz/gn;
        float sse = nx*nx + ny*ny + nz*nz;

        // laplacian
        float d = fmaxf(deg[v], 1.0f);
        float lx = nsum[3*v]/d - px, ly = nsum[3*v+1]/d - py, lz = nsum[3*v+2]/d - pz;
        float lapn = sqrtf(lx*lx + ly*ly + lz*lz);

        // grid-sample target (nearest, align_corners=True, zeros padding)
        int ix = (int)rintf(px * 95.0f), iy = (int)rintf(py * 95.0f), iz = (int)rintf(pz * 95.0f);
        bool inb = (ix >= 0) & (ix < 96) & (iy >= 0) & (iy < 96) & (iz >= 0) & (iz < 96);
        int ixc = min(max(ix, 0), 95), iyc = min(max(iy, 0), 95), izc = min(max(iz, 0), 95);
        bool pos = inb && (label[(izc*96 + iyc)*96 + ixc] == 1);

        float p = fminf(fmaxf(relpos[v], EPSF), 1.0f - EPSF);
        float om = 1.0f - p;
        float pcnt = 0.0f, sx = 0.0f, sy = 0.0f;
        if (pos) { pcnt = 1.0f; sx = om*om*logf(p); }
        else     { sy = p*p*logf(om); }

        float r0 = wave_sum(dmin);
        float r1 = wave_sum(sse);
        float r2 = wave_sum(lapn);
        float r3 = wave_sum(pcnt);
        float r4 = wave_sum(sx);
        float r5 = wave_sum(sy);
        if ((threadIdx.x & 63) == 0) {
            atomicAdd(&scal[0], r0);
            atomicAdd(&scal[5], r1);
            atomicAdd(&scal[6], r2);
            atomicAdd(&scal[2], r3);
            atomicAdd(&scal[3], r4);
            atomicAdd(&scal[4], r5);
        }
    } else {
        int i = (blockIdx.x - FIN_PRED_BLOCKS) * 256 + threadIdx.x;
        float val = 0.0f;
        if (i < NG) {
            float4 Q = sortG[i];
            float dmin; int dummy;
            grid_nn(Q.x, Q.y, Q.z, sortP, startP, endP, false, dmin, dummy);
            val = dmin;
        }
        float r = wave_sum(val);
        if ((threadIdx.x & 63) == 0) atomicAdd(&scal[1], r);
    }

    // last-block combine (device-scope atomics; fence orders our adds before ticket)
    __threadfence();
    __shared__ int is_last;
    if (threadIdx.x == 0) {
        unsigned t = atomicAdd(ticket, 1u);
        is_last = (t == FIN_TOTAL - 1) ? 1 : 0;
    }
    __syncthreads();
    if (is_last && threadIdx.x == 0) {
        float sum_row = atomicAdd(&scal[0], 0.0f);
        float sum_col = atomicAdd(&scal[1], 0.0f);
        float pc      = atomicAdd(&scal[2], 0.0f);
        float SX      = atomicAdd(&scal[3], 0.0f);
        float SY      = atomicAdd(&scal[4], 0.0f);
        float sse     = atomicAdd(&scal[5], 0.0f);
        float lap     = atomicAdd(&scal[6], 0.0f);
        float tot = (float)NP;
        float alpha = (tot - pc) / (tot + EPSF);
        float spatial = (-alpha * SX - (1.0f - alpha) * SY) / (tot + EPSF);
        float distance = sum_row / (float)NP + sum_col / (float)NG;
        float normal = sse / (float)(NP * 3);
        float lapm = lap / (float)NP;
        out[0] = spatial + 1.0f * distance + 0.01f * normal + 0.1f * lapm;
    }
}

extern "C" void kernel_launch(void* const* d_in, const int* in_sizes, int n_in,
                              void* d_out, int out_size, void* d_ws, size_t ws_size,
                              hipStream_t stream) {
    const float* pred   = (const float*)d_in[0];   // [8192,3]
    const float* relpos = (const float*)d_in[1];   // [8192]
    const float* gt     = (const float*)d_in[2];   // [12000,3]
    const int*   pfaces = (const int*)d_in[3];     // [16384,3]
    const int*   gfaces = (const int*)d_in[4];     // [24000,3]
    const int*   label  = (const int*)d_in[5];     // [1,1,96,96,96]
    float* out = (float*)d_out;

    char* ws = (char*)d_ws;
    unsigned* startP = (unsigned*)(ws + OFF_STARTP);
    unsigned* curP   = (unsigned*)(ws + OFF_CURP);
    unsigned* startG = (unsigned*)(ws + OFF_STARTG);
    unsigned* curG   = (unsigned*)(ws + OFF_CURG);
    float4*   sortP  = (float4*)(ws + OFF_SORTP);
    float4*   sortG  = (float4*)(ws + OFF_SORTG);
    float*    gtn    = (float*)(ws + OFF_GTN);
    float*    pnn    = (float*)(ws + OFF_PNN);
    float*    nsum   = (float*)(ws + OFF_NSUM);
    float*    deg    = (float*)(ws + OFF_DEG);
    float*    scal   = (float*)(ws + OFF_SCAL);
    unsigned* ticket = (unsigned*)(ws + OFF_TICKET);

    // d1: build histograms+scans (block 0) || zero accumulators (blocks 1..)
    int zero_blocks = (N_ZERO + 1023) / 1024;      // 92
    hipLaunchKernelGGL(build_kernel, dim3(1 + zero_blocks), dim3(1024), 0, stream,
                       pred, gt, startP, curP, startG, curG, gtn);
    // d2: scatter into cell order + face/laplacian scatter
    hipLaunchKernelGGL(scatter_faces_kernel, dim3(SCAT_BLOCKS + FACE_BLOCKS), dim3(256), 0, stream,
                       pred, pfaces, gt, gfaces, curP, curG, sortP, sortG,
                       gtn, pnn, nsum, deg);
    // d3: grid-NN query + all loss terms + combine
    hipLaunchKernelGGL(query_finalize_kernel, dim3(FIN_TOTAL), dim3(256), 0, stream,
                       relpos, label, sortP, sortG, startP, curP, startG, curG,
                       pnn, gtn, nsum, deg, scal, ticket, out);
}